// Round 16
// baseline (243.526 us; speedup 1.0000x reference)
//
#include <hip/hip_runtime.h>
#include <hip/hip_bf16.h>
#include <cstdint>

// ---------------------------------------------------------------------------
// TagProjector fused kernel (R16):
//   flat = tab[clamp(ids,0)]                  [51200, 512]  (gather, f32->bf16)
//   h    = gelu_tanh(flat @ w1 + b1)          [51200, 1024] (bf16 MFMA)
//   y    = h @ w2 + b2                        [51200, 256]  (bf16 MFMA, reg acc)
//   out  = mask ? 0 : y / max(||y||, 1e-12)   [51200, 256]  f32
//
// R16 = R15 (AGPR accumulators via inline-asm MFMA, depth-3 4-slot W
// rotations) + HAZARD FENCES. R15's absmax 2.2e-2 failure: inline-asm MFMA
// bypasses LLVM's hazard recognizer, so v_accvgpr_read of MFMA results was
// emitted inside the MFMA result-latency window. Fix: asm fences carrying
// "+a" ties on EVERY accumulator (dataflow-ordered, can't be hoisted past):
//   - s_nop 7;7;3 (20cyc) after each MFMA loop, before C-level acc reads
//   - s_nop 1 after zero-init (VALU-write -> MFMA-SrcC hazard)
// Decisive counters: pass + WRITE == 51.2MB + FETCH ~= 73MB (spill gone).
// ---------------------------------------------------------------------------

typedef __bf16 bf16;
typedef bf16  bf16x8 __attribute__((ext_vector_type(8)));
typedef bf16  bf16x4 __attribute__((ext_vector_type(4)));
typedef float f32x4  __attribute__((ext_vector_type(4)));

#define D_IN    512
#define D_HID   1024
#define D_OUT   256
#define MT      64        // rows per full tile
#define RPB     200       // rows per block (51200 / 256)
#define NBLK    256
#define CHUNK   256       // N1 chunk width
#define NCH     4         // D_HID / CHUNK
#define NKS1    16        // D_IN / 32
#define NKS2C   8         // CHUNK / 32
#define THREADS 512

// LDS layout (bytes)
#define OFF_A    0                          // 64*512*2       = 65536 (A tile, swizzled)
#define OFF_H    65536                      // 2 * 64*256*2   = 65536 (H chunk dbuf)
#define OFF_NS   (65536 + 65536)            // 64*8*4         = 2048  (norm partials)
#define OFF_RID  (65536 + 65536 + 2048)     // 64*4           = 256   (row ids)
#define LDS_TOTAL (65536 + 65536 + 2048 + 256)   // 133376 -> 1 block/CU

// ws layout: W1f bf16 [64 ct][16 ks][64 lane][8]  (1 MB)
//            W2f bf16 [16 ct][32 ks][64 lane][8]  (512 KB)
#define W1F_ELEMS (64 * 16 * 64 * 8)   // 524288

// MFMA with the accumulator pinned to AGPRs (frees ~64 arch VGPRs from the
// hard 128 cap). D and C tied via "+a"; A/B fragments in VGPRs.
__device__ __forceinline__ void mfma_agpr(f32x4& d, bf16x8 a, bf16x8 b) {
  asm("v_mfma_f32_16x16x32_bf16 %0, %1, %2, %0" : "+a"(d) : "v"(a), "v"(b));
}

// Hazard fence: 20 cycles of nops, data-tied to every accumulator so no
// subsequent accvgpr_read can be scheduled before it (and it can't be
// scheduled before any MFMA writing these accs).
template<int RT>
__device__ __forceinline__ void fence_read(f32x4 (&a)[RT][2]) {
  if constexpr (RT == 4)
    asm volatile("s_nop 7\n\ts_nop 7\n\ts_nop 3"
        : "+a"(a[0][0]), "+a"(a[0][1]), "+a"(a[1][0]), "+a"(a[1][1]),
          "+a"(a[2][0]), "+a"(a[2][1]), "+a"(a[3][0]), "+a"(a[3][1]));
  else
    asm volatile("s_nop 7\n\ts_nop 7\n\ts_nop 3"
        : "+a"(a[0][0]), "+a"(a[0][1]));
}

// VALU-write(init) -> MFMA-SrcC hazard fence (2 cycles).
template<int RT>
__device__ __forceinline__ void fence_init(f32x4 (&a)[RT][2]) {
  if constexpr (RT == 4)
    asm volatile("s_nop 1"
        : "+a"(a[0][0]), "+a"(a[0][1]), "+a"(a[1][0]), "+a"(a[1][1]),
          "+a"(a[2][0]), "+a"(a[2][1]), "+a"(a[3][0]), "+a"(a[3][1]));
  else
    asm volatile("s_nop 1" : "+a"(a[0][0]), "+a"(a[0][1]));
}

__device__ __forceinline__ float gelu_tanh(float x) {
  // jax.nn.gelu default (approximate=True): 0.5x(1+tanh(u)) == x*sigmoid(2u)
  float u = 0.7978845608028654f * (x + 0.044715f * x * x * x);
  return x * __builtin_amdgcn_rcpf(1.0f + __expf(-2.0f * u));
}

// ------------------- prep: f32 weights -> bf16 fragment order -------------------
__global__ void prep_weights(const float* __restrict__ w1, const float* __restrict__ w2,
                             bf16* __restrict__ w1f, bf16* __restrict__ w2f) {
  const int t = blockIdx.x * blockDim.x + threadIdx.x;
  if (t < 65536) {                       // W1: 64 ct * 16 ks * 64 lanes
    const int l  = t & 63;
    const int ks = (t >> 6) & 15;
    const int ct = t >> 10;
    const int col   = ct * 16 + (l & 15);
    const int kbase = ks * 32 + (l >> 4) * 8;
    bf16x8 o;
#pragma unroll
    for (int j = 0; j < 8; ++j) o[j] = (bf16)w1[(size_t)(kbase + j) * D_HID + col];
    *(bf16x8*)(w1f + (size_t)t * 8) = o;
  } else if (t < 65536 + 32768) {        // W2: 16 ct * 32 ks * 64 lanes
    const int t2 = t - 65536;
    const int l   = t2 & 63;
    const int ks2 = (t2 >> 6) & 31;
    const int ct2 = t2 >> 11;
    const int col   = ct2 * 16 + (l & 15);
    const int kbase = ks2 * 32 + (l >> 4) * 8;
    bf16x8 o;
#pragma unroll
    for (int j = 0; j < 8; ++j) o[j] = (bf16)w2[(size_t)(kbase + j) * D_OUT + col];
    *(bf16x8*)(w2f + (size_t)t2 * 8) = o;
  }
}

// ----------------------------- tile body ---------------------------------
// RT: number of 16-row sub-tiles (4 = full 64-row tile, 1 = 16-row tail)
// RV: valid rows in this tile (ids reads + stores masked beyond RV)
template<int RT, int RV>
__device__ __forceinline__ void process_tile(
    const float* __restrict__ tab, const int* __restrict__ ids,
    const bf16* __restrict__ w1f, const bf16* __restrict__ w2f,
    const float* __restrict__ b1, const float* __restrict__ b2,
    float* __restrict__ out,
    bf16* As, bf16* Hb, float* Ns, int* Rid,
    int row0, int tid, int w, int l, int lg, int lc) {

  __syncthreads();  // previous tile's epilogue fully done (Rid/Ns reads)

  // ---- A gather: 64 rows x 512 f32 -> bf16 swizzled LDS (8 thr/row) ----
  {
    const int row = tid >> 3;        // 0..63
    const int q   = tid & 7;
    int id = -1;
    if (RV == MT || row < RV) id = ids[row0 + row];   // no OOB reads on tail
    if (q == 0) Rid[row] = id;
    const float* src = tab + (size_t)(id < 0 ? 0 : id) * D_IN;
#pragma unroll
    for (int i = 0; i < 16; ++i) {
      const int c4 = i * 32 + q * 4;
      const float4 v = *(const float4*)(src + c4);
      bf16x4 b;
      b[0] = (bf16)v.x; b[1] = (bf16)v.y; b[2] = (bf16)v.z; b[3] = (bf16)v.w;
      *(bf16x4*)&As[row * 512 + (c4 ^ ((row & 15) << 3))] = b;
    }
  }
  __syncthreads();

  // persistent GEMM2 accumulators (AGPR): rows rt*16+lg*4+r, cols (w*2+t)*16+lc
  f32x4 acc2[RT][2];
#pragma unroll
  for (int rt = 0; rt < RT; ++rt)
#pragma unroll
    for (int t = 0; t < 2; ++t) acc2[rt][t] = (f32x4){0.f, 0.f, 0.f, 0.f};
  fence_init<RT>(acc2);

  for (int c = 0; c < NCH; ++c) {
    bf16* Hs = Hb + (c & 1) * (MT * CHUNK);

    // ===== GEMM1: h_chunk = A @ W1[:, c*256:+256], depth-3 W prefetch =====
    f32x4 acc1[RT][2];
#pragma unroll
    for (int rt = 0; rt < RT; ++rt)
#pragma unroll
      for (int t = 0; t < 2; ++t) acc1[rt][t] = (f32x4){0.f, 0.f, 0.f, 0.f};
    fence_init<RT>(acc1);

    // fragment: ((ct*16 + ks)*64 + l)*8, ct = c*16 + w*2 + t
    const bf16* w1p = w1f + (((size_t)(c * 16 + w * 2) * 16) * 64 + l) * 8;
    bf16x8 wr1[4][2];   // 4-slot rotation, depth-3: load (ks+3)&3, read ks&3
#pragma unroll
    for (int pf = 0; pf < 3; ++pf)
#pragma unroll
      for (int t = 0; t < 2; ++t)
        wr1[pf][t] = *(const bf16x8*)(w1p + (size_t)t * 8192 + (size_t)pf * 512);

#pragma unroll
    for (int ks = 0; ks < NKS1; ++ks) {
      if (ks + 3 < NKS1) {
#pragma unroll
        for (int t = 0; t < 2; ++t)
          wr1[(ks + 3) & 3][t] =
              *(const bf16x8*)(w1p + (size_t)t * 8192 + (size_t)(ks + 3) * 512);
      }
      bf16x8 af[RT];
#pragma unroll
      for (int rt = 0; rt < RT; ++rt) {
        const int e = ks * 32 + lg * 8;
        af[rt] = *(const bf16x8*)&As[(rt * 16 + lc) * 512 + (e ^ (lc << 3))];
      }
#pragma unroll
      for (int t = 0; t < 2; ++t)
#pragma unroll
        for (int rt = 0; rt < RT; ++rt)
          mfma_agpr(acc1[rt][t], af[rt], wr1[ks & 3][t]);
    }
    fence_read<RT>(acc1);   // MFMA->VALU(accvgpr_read) hazard cover

    // ---- GEMM2's initial W2 prefetch issued EARLY (independent of H) ----
    const bf16* w2p = w2f + (((size_t)(w * 2) * 32 + c * 8) * 64 + l) * 8;
    bf16x8 wr2[4][2];
#pragma unroll
    for (int pf = 0; pf < 3; ++pf)
#pragma unroll
      for (int t = 0; t < 2; ++t)
        wr2[pf][t] = *(const bf16x8*)(w2p + (size_t)t * 16384 + (size_t)pf * 512);

    // ---- bias + GELU -> bf16 h chunk in LDS (swizzled, double-buffered) ----
#pragma unroll
    for (int t = 0; t < 2; ++t) {
      const int pos    = w * 2 + t;
      const float bias = b1[c * CHUNK + pos * 16 + lc];
#pragma unroll
      for (int rt = 0; rt < RT; ++rt) {
#pragma unroll
        for (int r = 0; r < 4; ++r) {
          const float x  = acc1[rt][t][r] + bias;
          const float hx = gelu_tanh(x);
          const int row  = rt * 16 + lg * 4 + r;
          const int e    = pos * 16 + lc;
          Hs[row * 256 + (e ^ ((row & 15) << 3))] = (bf16)hx;
        }
      }
    }
    __syncthreads();   // h chunk visible; wr2 loads were in flight during wait

    // ===== GEMM2: y += h_chunk @ W2[c*256:+256, :], depth-3 W prefetch =====
#pragma unroll
    for (int s2 = 0; s2 < NKS2C; ++s2) {
      if (s2 + 3 < NKS2C) {
#pragma unroll
        for (int t = 0; t < 2; ++t)
          wr2[(s2 + 3) & 3][t] =
              *(const bf16x8*)(w2p + (size_t)t * 16384 + (size_t)(s2 + 3) * 512);
      }
      bf16x8 hf[RT];
#pragma unroll
      for (int rt = 0; rt < RT; ++rt) {
        const int e = s2 * 32 + lg * 8;
        hf[rt] = *(const bf16x8*)&Hs[(rt * 16 + lc) * 256 + (e ^ (lc << 3))];
      }
#pragma unroll
      for (int t = 0; t < 2; ++t)
#pragma unroll
        for (int rt = 0; rt < RT; ++rt)
          mfma_agpr(acc2[rt][t], hf[rt], wr2[s2 & 3][t]);
    }
  }
  fence_read<RT>(acc2);   // cover before epilogue accvgpr reads

  // ---- epilogue: +b2, row L2-norm, pad mask, store (no yv array) ----
  float bias2[2];
  bias2[0] = b2[(w * 2 + 0) * 16 + lc];
  bias2[1] = b2[(w * 2 + 1) * 16 + lc];

  float ssq[RT][4];
#pragma unroll
  for (int rt = 0; rt < RT; ++rt)
#pragma unroll
    for (int r = 0; r < 4; ++r) ssq[rt][r] = 0.f;

#pragma unroll
  for (int t = 0; t < 2; ++t)
#pragma unroll
    for (int rt = 0; rt < RT; ++rt)
#pragma unroll
      for (int r = 0; r < 4; ++r) {
        const float v = acc2[rt][t][r] + bias2[t];
        ssq[rt][r] += v * v;
      }

#pragma unroll
  for (int rt = 0; rt < RT; ++rt)
#pragma unroll
    for (int r = 0; r < 4; ++r) {
      float s = ssq[rt][r];
      s += __shfl_xor(s, 1);
      s += __shfl_xor(s, 2);
      s += __shfl_xor(s, 4);
      s += __shfl_xor(s, 8);
      ssq[rt][r] = s;   // per-wave partial (32 of 256 cols)
    }
  if (lc == 0) {
#pragma unroll
    for (int rt = 0; rt < RT; ++rt)
#pragma unroll
      for (int r = 0; r < 4; ++r)
        Ns[(rt * 16 + lg * 4 + r) * 8 + w] = ssq[rt][r];
  }
  __syncthreads();

#pragma unroll
  for (int rt = 0; rt < RT; ++rt)
#pragma unroll
    for (int r = 0; r < 4; ++r) {
      const int row = rt * 16 + lg * 4 + r;
      if (RV == MT || row < RV) {
        float ss = 0.f;
#pragma unroll
        for (int ww = 0; ww < 8; ++ww) ss += Ns[row * 8 + ww];
        const float scale = (Rid[row] < 0) ? 0.f : (1.f / fmaxf(sqrtf(ss), 1e-12f));
#pragma unroll
        for (int t = 0; t < 2; ++t)
          out[(size_t)(row0 + row) * D_OUT + (w * 2 + t) * 16 + lc] =
              (acc2[rt][t][r] + bias2[t]) * scale;
      }
    }
}

// ----------------------------- fused main kernel --------------------------------
__global__ __launch_bounds__(THREADS, 1)
void tagproj_fused(const float* __restrict__ tab, const int* __restrict__ ids,
                   const bf16* __restrict__ w1f, const bf16* __restrict__ w2f,
                   const float* __restrict__ b1, const float* __restrict__ b2,
                   float* __restrict__ out) {
  extern __shared__ __align__(16) char lds[];
  bf16*  As  = (bf16*)(lds + OFF_A);
  bf16*  Hb  = (bf16*)(lds + OFF_H);
  float* Ns  = (float*)(lds + OFF_NS);
  int*   Rid = (int*)(lds + OFF_RID);

  const int tid = threadIdx.x;
  const int w   = tid >> 6;   // wave 0..7
  const int l   = tid & 63;
  const int lg  = l >> 4;     // k-group 0..3
  const int lc  = l & 15;     // row/col within 16-tile
  const int base = blockIdx.x * RPB;

  // 3 full 64-row tiles + one 16-row tail tile (8 valid) = 200 rows, balanced
  for (int tt = 0; tt < 3; ++tt)
    process_tile<4, MT>(tab, ids, w1f, w2f, b1, b2, out,
                        As, Hb, Ns, Rid, base + tt * MT, tid, w, l, lg, lc);
  process_tile<1, 8>(tab, ids, w1f, w2f, b1, b2, out,
                     As, Hb, Ns, Rid, base + 192, tid, w, l, lg, lc);
}

// --------------------------------- launcher ---------------------------------
extern "C" void kernel_launch(void* const* d_in, const int* in_sizes, int n_in,
                              void* d_out, int out_size, void* d_ws, size_t ws_size,
                              hipStream_t stream) {
  const float* tab = (const float*)d_in[0];
  const float* w1  = (const float*)d_in[1];
  const float* b1  = (const float*)d_in[2];
  const float* w2  = (const float*)d_in[3];
  const float* b2  = (const float*)d_in[4];
  const int*   ids = (const int*)d_in[5];
  float* out = (float*)d_out;

  bf16* w1f = (bf16*)d_ws;
  bf16* w2f = w1f + W1F_ELEMS;

  hipLaunchKernelGGL(prep_weights, dim3(384), dim3(256), 0, stream, w1, w2, w1f, w2f);

  (void)hipFuncSetAttribute(reinterpret_cast<const void*>(tagproj_fused),
                            hipFuncAttributeMaxDynamicSharedMemorySize, LDS_TOTAL);
  hipLaunchKernelGGL(tagproj_fused, dim3(NBLK), dim3(THREADS), LDS_TOTAL, stream,
                     tab, ids, w1f, w2f, b1, b2, out);
}

// Round 17
// 214.199 us; speedup vs baseline: 1.1369x; 1.1369x over previous
//
#include <hip/hip_runtime.h>
#include <hip/hip_bf16.h>
#include <cstdint>

// ---------------------------------------------------------------------------
// TagProjector fused kernel (R17):
//   flat = tab[clamp(ids,0)]                  [51200, 512]  (gather, f32->bf16)
//   h    = gelu_tanh(flat @ w1 + b1)          [51200, 1024] (bf16 MFMA)
//   y    = h @ w2 + b2                        [51200, 256]  (bf16 MFMA, reg acc)
//   out  = mask ? 0 : y / max(||y||, 1e-12)   [51200, 256]  f32
//
// R17: make peak live registers GENUINELY < the hard 128 arch-VGPR cap
// (R9-R16: cap is immovable; R16's AGPR asm path regressed badly).
// Change vs R14: GEMM1 split over rows into 2 passes of 2 sub-tiles
// (acc1 32->16, af 16->8); freed regs restore depth-3 4-slot rotations
// (233cyc cover GEMM1, 466cyc GEMM2). W1 re-read per pass hits L2 only.
// Peaks: GEMM1 ~105, GEMM2 ~95 < 128 -> no scratch at all.
// Decisive: VGPR < 128, WRITE == 51.2MB, FETCH ~= 73MB.
// ---------------------------------------------------------------------------

typedef __bf16 bf16;
typedef bf16  bf16x8 __attribute__((ext_vector_type(8)));
typedef bf16  bf16x4 __attribute__((ext_vector_type(4)));
typedef float f32x4  __attribute__((ext_vector_type(4)));

#define D_IN    512
#define D_HID   1024
#define D_OUT   256
#define MT      64        // rows per full tile
#define RPB     200       // rows per block (51200 / 256)
#define NBLK    256
#define CHUNK   256       // N1 chunk width
#define NCH     4         // D_HID / CHUNK
#define NKS1    16        // D_IN / 32
#define NKS2C   8         // CHUNK / 32
#define THREADS 512

// LDS layout (bytes)
#define OFF_A    0                          // 64*512*2       = 65536 (A tile, swizzled)
#define OFF_H    65536                      // 2 * 64*256*2   = 65536 (H chunk dbuf)
#define OFF_NS   (65536 + 65536)            // 64*8*4         = 2048  (norm partials)
#define OFF_RID  (65536 + 65536 + 2048)     // 64*4           = 256   (row ids)
#define LDS_TOTAL (65536 + 65536 + 2048 + 256)   // 133376 -> 1 block/CU

// ws layout: W1f bf16 [64 ct][16 ks][64 lane][8]  (1 MB)
//            W2f bf16 [16 ct][32 ks][64 lane][8]  (512 KB)
#define W1F_ELEMS (64 * 16 * 64 * 8)   // 524288

__device__ __forceinline__ float gelu_tanh(float x) {
  // jax.nn.gelu default (approximate=True): 0.5x(1+tanh(u)) == x*sigmoid(2u)
  float u = 0.7978845608028654f * (x + 0.044715f * x * x * x);
  return x * __builtin_amdgcn_rcpf(1.0f + __expf(-2.0f * u));
}

// ------------------- prep: f32 weights -> bf16 fragment order -------------------
__global__ void prep_weights(const float* __restrict__ w1, const float* __restrict__ w2,
                             bf16* __restrict__ w1f, bf16* __restrict__ w2f) {
  const int t = blockIdx.x * blockDim.x + threadIdx.x;
  if (t < 65536) {                       // W1: 64 ct * 16 ks * 64 lanes
    const int l  = t & 63;
    const int ks = (t >> 6) & 15;
    const int ct = t >> 10;
    const int col   = ct * 16 + (l & 15);
    const int kbase = ks * 32 + (l >> 4) * 8;
    bf16x8 o;
#pragma unroll
    for (int j = 0; j < 8; ++j) o[j] = (bf16)w1[(size_t)(kbase + j) * D_HID + col];
    *(bf16x8*)(w1f + (size_t)t * 8) = o;
  } else if (t < 65536 + 32768) {        // W2: 16 ct * 32 ks * 64 lanes
    const int t2 = t - 65536;
    const int l   = t2 & 63;
    const int ks2 = (t2 >> 6) & 31;
    const int ct2 = t2 >> 11;
    const int col   = ct2 * 16 + (l & 15);
    const int kbase = ks2 * 32 + (l >> 4) * 8;
    bf16x8 o;
#pragma unroll
    for (int j = 0; j < 8; ++j) o[j] = (bf16)w2[(size_t)(kbase + j) * D_OUT + col];
    *(bf16x8*)(w2f + (size_t)t2 * 8) = o;
  }
}

// ----------------------------- tile body ---------------------------------
// RT: number of 16-row sub-tiles (4 = full 64-row tile, 1 = 16-row tail)
// RV: valid rows in this tile (ids reads + stores masked beyond RV)
template<int RT, int RV>
__device__ __forceinline__ void process_tile(
    const float* __restrict__ tab, const int* __restrict__ ids,
    const bf16* __restrict__ w1f, const bf16* __restrict__ w2f,
    const float* __restrict__ b1, const float* __restrict__ b2,
    float* __restrict__ out,
    bf16* As, bf16* Hb, float* Ns, int* Rid,
    int row0, int tid, int w, int l, int lg, int lc) {

  constexpr int RTP = (RT >= 2) ? 2 : 1;   // sub-tiles per GEMM1 pass
  constexpr int NP  = RT / RTP;            // GEMM1 passes

  __syncthreads();  // previous tile's epilogue fully done (Rid/Ns reads)

  // ---- A gather: 64 rows x 512 f32 -> bf16 swizzled LDS (8 thr/row) ----
  {
    const int row = tid >> 3;        // 0..63
    const int q   = tid & 7;
    int id = -1;
    if (RV == MT || row < RV) id = ids[row0 + row];   // no OOB reads on tail
    if (q == 0) Rid[row] = id;
    const float* src = tab + (size_t)(id < 0 ? 0 : id) * D_IN;
#pragma unroll
    for (int i = 0; i < 16; ++i) {
      const int c4 = i * 32 + q * 4;
      const float4 v = *(const float4*)(src + c4);
      bf16x4 b;
      b[0] = (bf16)v.x; b[1] = (bf16)v.y; b[2] = (bf16)v.z; b[3] = (bf16)v.w;
      *(bf16x4*)&As[row * 512 + (c4 ^ ((row & 15) << 3))] = b;
    }
  }
  __syncthreads();

  // persistent GEMM2 accumulators: rows g*16+lg*4+r, cols (w*2+t)*16+lc
  f32x4 acc2[RT][2];
#pragma unroll
  for (int g = 0; g < RT; ++g)
#pragma unroll
    for (int t = 0; t < 2; ++t) acc2[g][t] = (f32x4){0.f, 0.f, 0.f, 0.f};

  for (int c = 0; c < NCH; ++c) {
    bf16* Hs = Hb + (c & 1) * (MT * CHUNK);

    // fragment: ((ct*16 + ks)*64 + l)*8, ct = c*16 + w*2 + t
    const bf16* w1p = w1f + (((size_t)(c * 16 + w * 2) * 16) * 64 + l) * 8;
    const bf16* w2p = w2f + (((size_t)(w * 2) * 32 + c * 8) * 64 + l) * 8;
    bf16x8 wr2[4][2];   // declared here; prefilled in last GEMM1 pass (hoist)

    // ===== GEMM1 in NP passes of RTP row-sub-tiles each =====
#pragma unroll
    for (int p = 0; p < NP; ++p) {
      f32x4 acc1[RTP][2];
#pragma unroll
      for (int rt = 0; rt < RTP; ++rt)
#pragma unroll
        for (int t = 0; t < 2; ++t) acc1[rt][t] = (f32x4){0.f, 0.f, 0.f, 0.f};

      bf16x8 wr1[4][2];   // 4-slot rotation, depth-3
#pragma unroll
      for (int pf = 0; pf < 3; ++pf)
#pragma unroll
        for (int t = 0; t < 2; ++t)
          wr1[pf][t] = *(const bf16x8*)(w1p + (size_t)t * 8192 + (size_t)pf * 512);

#pragma unroll
      for (int ks = 0; ks < NKS1; ++ks) {
        if (ks + 3 < NKS1) {
#pragma unroll
          for (int t = 0; t < 2; ++t)
            wr1[(ks + 3) & 3][t] =
                *(const bf16x8*)(w1p + (size_t)t * 8192 + (size_t)(ks + 3) * 512);
        }
        bf16x8 af[RTP];
#pragma unroll
        for (int rt = 0; rt < RTP; ++rt) {
          const int row = (p * RTP + rt) * 16 + lc;
          const int e   = ks * 32 + lg * 8;
          af[rt] = *(const bf16x8*)&As[row * 512 + (e ^ (lc << 3))];
        }
#pragma unroll
        for (int t = 0; t < 2; ++t)
#pragma unroll
          for (int rt = 0; rt < RTP; ++rt)
            acc1[rt][t] = __builtin_amdgcn_mfma_f32_16x16x32_bf16(
                af[rt], wr1[ks & 3][t], acc1[rt][t], 0, 0, 0);
      }

      // last pass: prefill wr2 early so its L2 latency hides under GELU+barrier
      if (p == NP - 1) {
#pragma unroll
        for (int pf = 0; pf < 3; ++pf)
#pragma unroll
          for (int t = 0; t < 2; ++t)
            wr2[pf][t] = *(const bf16x8*)(w2p + (size_t)t * 16384 + (size_t)pf * 512);
      }

      // ---- bias + GELU for this pass's rows -> bf16 h chunk in LDS ----
#pragma unroll
      for (int t = 0; t < 2; ++t) {
        const int pos    = w * 2 + t;
        const float bias = b1[c * CHUNK + pos * 16 + lc];
#pragma unroll
        for (int rt = 0; rt < RTP; ++rt) {
#pragma unroll
          for (int r = 0; r < 4; ++r) {
            const float x  = acc1[rt][t][r] + bias;
            const float hx = gelu_tanh(x);
            const int row  = (p * RTP + rt) * 16 + lg * 4 + r;
            const int e    = pos * 16 + lc;
            Hs[row * 256 + (e ^ ((row & 15) << 3))] = (bf16)hx;
          }
        }
      }
    }
    __syncthreads();   // h chunk visible; wr2 loads were in flight during wait

    // ===== GEMM2: y += h_chunk @ W2[c*256:+256, :], depth-3 W prefetch =====
#pragma unroll
    for (int s2 = 0; s2 < NKS2C; ++s2) {
      if (s2 + 3 < NKS2C) {
#pragma unroll
        for (int t = 0; t < 2; ++t)
          wr2[(s2 + 3) & 3][t] =
              *(const bf16x8*)(w2p + (size_t)t * 16384 + (size_t)(s2 + 3) * 512);
      }
      bf16x8 hf[RT];
#pragma unroll
      for (int g = 0; g < RT; ++g) {
        const int e = s2 * 32 + lg * 8;
        hf[g] = *(const bf16x8*)&Hs[(g * 16 + lc) * 256 + (e ^ (lc << 3))];
      }
#pragma unroll
      for (int t = 0; t < 2; ++t)
#pragma unroll
        for (int g = 0; g < RT; ++g)
          acc2[g][t] = __builtin_amdgcn_mfma_f32_16x16x32_bf16(
              hf[g], wr2[s2 & 3][t], acc2[g][t], 0, 0, 0);
    }
  }

  // ---- epilogue: +b2, row L2-norm, pad mask, store (no yv array) ----
  float bias2[2];
  bias2[0] = b2[(w * 2 + 0) * 16 + lc];
  bias2[1] = b2[(w * 2 + 1) * 16 + lc];

  float ssq[RT][4];
#pragma unroll
  for (int g = 0; g < RT; ++g)
#pragma unroll
    for (int r = 0; r < 4; ++r) ssq[g][r] = 0.f;

#pragma unroll
  for (int t = 0; t < 2; ++t)
#pragma unroll
    for (int g = 0; g < RT; ++g)
#pragma unroll
      for (int r = 0; r < 4; ++r) {
        const float v = acc2[g][t][r] + bias2[t];
        ssq[g][r] += v * v;
      }

#pragma unroll
  for (int g = 0; g < RT; ++g)
#pragma unroll
    for (int r = 0; r < 4; ++r) {
      float s = ssq[g][r];
      s += __shfl_xor(s, 1);
      s += __shfl_xor(s, 2);
      s += __shfl_xor(s, 4);
      s += __shfl_xor(s, 8);
      ssq[g][r] = s;   // per-wave partial (32 of 256 cols)
    }
  if (lc == 0) {
#pragma unroll
    for (int g = 0; g < RT; ++g)
#pragma unroll
      for (int r = 0; r < 4; ++r)
        Ns[(g * 16 + lg * 4 + r) * 8 + w] = ssq[g][r];
  }
  __syncthreads();

#pragma unroll
  for (int g = 0; g < RT; ++g)
#pragma unroll
    for (int r = 0; r < 4; ++r) {
      const int row = g * 16 + lg * 4 + r;
      if (RV == MT || row < RV) {
        float ss = 0.f;
#pragma unroll
        for (int ww = 0; ww < 8; ++ww) ss += Ns[row * 8 + ww];
        const float scale = (Rid[row] < 0) ? 0.f : (1.f / fmaxf(sqrtf(ss), 1e-12f));
#pragma unroll
        for (int t = 0; t < 2; ++t)
          out[(size_t)(row0 + row) * D_OUT + (w * 2 + t) * 16 + lc] =
              (acc2[g][t][r] + bias2[t]) * scale;
      }
    }
}

// ----------------------------- fused main kernel --------------------------------
__global__ __launch_bounds__(THREADS, 1)
void tagproj_fused(const float* __restrict__ tab, const int* __restrict__ ids,
                   const bf16* __restrict__ w1f, const bf16* __restrict__ w2f,
                   const float* __restrict__ b1, const float* __restrict__ b2,
                   float* __restrict__ out) {
  extern __shared__ __align__(16) char lds[];
  bf16*  As  = (bf16*)(lds + OFF_A);
  bf16*  Hb  = (bf16*)(lds + OFF_H);
  float* Ns  = (float*)(lds + OFF_NS);
  int*   Rid = (int*)(lds + OFF_RID);

  const int tid = threadIdx.x;
  const int w   = tid >> 6;   // wave 0..7
  const int l   = tid & 63;
  const int lg  = l >> 4;     // k-group 0..3
  const int lc  = l & 15;     // row/col within 16-tile
  const int base = blockIdx.x * RPB;

  // 3 full 64-row tiles + one 16-row tail tile (8 valid) = 200 rows, balanced
  for (int tt = 0; tt < 3; ++tt)
    process_tile<4, MT>(tab, ids, w1f, w2f, b1, b2, out,
                        As, Hb, Ns, Rid, base + tt * MT, tid, w, l, lg, lc);
  process_tile<1, 8>(tab, ids, w1f, w2f, b1, b2, out,
                     As, Hb, Ns, Rid, base + 192, tid, w, l, lg, lc);
}

// --------------------------------- launcher ---------------------------------
extern "C" void kernel_launch(void* const* d_in, const int* in_sizes, int n_in,
                              void* d_out, int out_size, void* d_ws, size_t ws_size,
                              hipStream_t stream) {
  const float* tab = (const float*)d_in[0];
  const float* w1  = (const float*)d_in[1];
  const float* b1  = (const float*)d_in[2];
  const float* w2  = (const float*)d_in[3];
  const float* b2  = (const float*)d_in[4];
  const int*   ids = (const int*)d_in[5];
  float* out = (float*)d_out;

  bf16* w1f = (bf16*)d_ws;
  bf16* w2f = w1f + W1F_ELEMS;

  hipLaunchKernelGGL(prep_weights, dim3(384), dim3(256), 0, stream, w1, w2, w1f, w2f);

  (void)hipFuncSetAttribute(reinterpret_cast<const void*>(tagproj_fused),
                            hipFuncAttributeMaxDynamicSharedMemorySize, LDS_TOTAL);
  hipLaunchKernelGGL(tagproj_fused, dim3(NBLK), dim3(THREADS), LDS_TOTAL, stream,
                     tab, ids, w1f, w2f, b1, b2, out);
}

// Round 18
// 159.720 us; speedup vs baseline: 1.5247x; 1.3411x over previous
//
#include <hip/hip_runtime.h>
#include <hip/hip_bf16.h>
#include <cstdint>

// ---------------------------------------------------------------------------
// TagProjector fused kernel (R18):
//   flat = tab[clamp(ids,0)]                  [51200, 512]  (gather, f32->bf16)
//   h    = gelu_tanh(flat @ w1 + b1)          [51200, 1024] (bf16 MFMA)
//   y    = h @ w2 + b2                        [51200, 256]  (bf16 MFMA, reg acc)
//   out  = mask ? 0 : y / max(||y||, 1e-12)   [51200, 256]  f32
//
// R18 = R14 (best, 164us: 3-slot depth-2 W rotations, wr2 hoist, balanced
// 256x200 grid) + GEMM1 split into 2 row-passes WITH sched_barrier(0) pass
// fences. R17's version of this split regressed because the unrolled passes
// were interleaved by the scheduler (pass-2 loads hoisted into pass-1 GELU),
// merging live ranges; the fence pins the boundary so acc1 truly drops
// 32->16 and af 16->8. Peak live ~100 (GEMM1) / ~95 (GEMM2) < the hard 128
// arch-VGPR cap -> scratch spill should finally die.
// Decisive counters: WRITE == 51.2MB, FETCH ~= 73MB, VGPR <= 128.
// ---------------------------------------------------------------------------

typedef __bf16 bf16;
typedef bf16  bf16x8 __attribute__((ext_vector_type(8)));
typedef bf16  bf16x4 __attribute__((ext_vector_type(4)));
typedef float f32x4  __attribute__((ext_vector_type(4)));

#define D_IN    512
#define D_HID   1024
#define D_OUT   256
#define MT      64        // rows per full tile
#define RPB     200       // rows per block (51200 / 256)
#define NBLK    256
#define CHUNK   256       // N1 chunk width
#define NCH     4         // D_HID / CHUNK
#define NKS1    16        // D_IN / 32
#define NKS2C   8         // CHUNK / 32
#define THREADS 512

// LDS layout (bytes)
#define OFF_A    0                          // 64*512*2       = 65536 (A tile, swizzled)
#define OFF_H    65536                      // 2 * 64*256*2   = 65536 (H chunk dbuf)
#define OFF_NS   (65536 + 65536)            // 64*8*4         = 2048  (norm partials)
#define OFF_RID  (65536 + 65536 + 2048)     // 64*4           = 256   (row ids)
#define LDS_TOTAL (65536 + 65536 + 2048 + 256)   // 133376 -> 1 block/CU

// ws layout: W1f bf16 [64 ct][16 ks][64 lane][8]  (1 MB)
//            W2f bf16 [16 ct][32 ks][64 lane][8]  (512 KB)
#define W1F_ELEMS (64 * 16 * 64 * 8)   // 524288

__device__ __forceinline__ float gelu_tanh(float x) {
  // jax.nn.gelu default (approximate=True): 0.5x(1+tanh(u)) == x*sigmoid(2u)
  float u = 0.7978845608028654f * (x + 0.044715f * x * x * x);
  return x * __builtin_amdgcn_rcpf(1.0f + __expf(-2.0f * u));
}

// ------------------- prep: f32 weights -> bf16 fragment order -------------------
__global__ void prep_weights(const float* __restrict__ w1, const float* __restrict__ w2,
                             bf16* __restrict__ w1f, bf16* __restrict__ w2f) {
  const int t = blockIdx.x * blockDim.x + threadIdx.x;
  if (t < 65536) {                       // W1: 64 ct * 16 ks * 64 lanes
    const int l  = t & 63;
    const int ks = (t >> 6) & 15;
    const int ct = t >> 10;
    const int col   = ct * 16 + (l & 15);
    const int kbase = ks * 32 + (l >> 4) * 8;
    bf16x8 o;
#pragma unroll
    for (int j = 0; j < 8; ++j) o[j] = (bf16)w1[(size_t)(kbase + j) * D_HID + col];
    *(bf16x8*)(w1f + (size_t)t * 8) = o;
  } else if (t < 65536 + 32768) {        // W2: 16 ct * 32 ks * 64 lanes
    const int t2 = t - 65536;
    const int l   = t2 & 63;
    const int ks2 = (t2 >> 6) & 31;
    const int ct2 = t2 >> 11;
    const int col   = ct2 * 16 + (l & 15);
    const int kbase = ks2 * 32 + (l >> 4) * 8;
    bf16x8 o;
#pragma unroll
    for (int j = 0; j < 8; ++j) o[j] = (bf16)w2[(size_t)(kbase + j) * D_OUT + col];
    *(bf16x8*)(w2f + (size_t)t2 * 8) = o;
  }
}

// ----------------------------- tile body ---------------------------------
// RT: number of 16-row sub-tiles (4 = full 64-row tile, 1 = 16-row tail)
// RV: valid rows in this tile (ids reads + stores masked beyond RV)
template<int RT, int RV>
__device__ __forceinline__ void process_tile(
    const float* __restrict__ tab, const int* __restrict__ ids,
    const bf16* __restrict__ w1f, const bf16* __restrict__ w2f,
    const float* __restrict__ b1, const float* __restrict__ b2,
    float* __restrict__ out,
    bf16* As, bf16* Hb, float* Ns, int* Rid,
    int row0, int tid, int w, int l, int lg, int lc) {

  constexpr int RTP = (RT >= 2) ? 2 : 1;   // row-sub-tiles per GEMM1 pass
  constexpr int NP  = RT / RTP;            // GEMM1 passes

  __syncthreads();  // previous tile's epilogue fully done (Rid/Ns reads)

  // ---- A gather: 64 rows x 512 f32 -> bf16 swizzled LDS (8 thr/row) ----
  {
    const int row = tid >> 3;        // 0..63
    const int q   = tid & 7;
    int id = -1;
    if (RV == MT || row < RV) id = ids[row0 + row];   // no OOB reads on tail
    if (q == 0) Rid[row] = id;
    const float* src = tab + (size_t)(id < 0 ? 0 : id) * D_IN;
#pragma unroll
    for (int i = 0; i < 16; ++i) {
      const int c4 = i * 32 + q * 4;
      const float4 v = *(const float4*)(src + c4);
      bf16x4 b;
      b[0] = (bf16)v.x; b[1] = (bf16)v.y; b[2] = (bf16)v.z; b[3] = (bf16)v.w;
      *(bf16x4*)&As[row * 512 + (c4 ^ ((row & 15) << 3))] = b;
    }
  }
  __syncthreads();

  // persistent GEMM2 accumulators: rows g*16+lg*4+r, cols (w*2+t)*16+lc
  f32x4 acc2[RT][2];
#pragma unroll
  for (int g = 0; g < RT; ++g)
#pragma unroll
    for (int t = 0; t < 2; ++t) acc2[g][t] = (f32x4){0.f, 0.f, 0.f, 0.f};

  for (int c = 0; c < NCH; ++c) {
    bf16* Hs = Hb + (c & 1) * (MT * CHUNK);

    // fragment: ((ct*16 + ks)*64 + l)*8, ct = c*16 + w*2 + t
    const bf16* w1p = w1f + (((size_t)(c * 16 + w * 2) * 16) * 64 + l) * 8;
    const bf16* w2p = w2f + (((size_t)(w * 2) * 32 + c * 8) * 64 + l) * 8;
    bf16x8 wr2[3][2];   // prefilled in last GEMM1 pass (hoist over barrier)

    // ===== GEMM1 in NP row-passes (acc1/af halved vs monolithic) =====
#pragma unroll
    for (int p = 0; p < NP; ++p) {
      // pass fence: forbid interleaving with the previous pass's GELU
      // (R17 regression: without this, live ranges merge and spill explodes)
      __builtin_amdgcn_sched_barrier(0);

      f32x4 acc1[RTP][2];
#pragma unroll
      for (int rt = 0; rt < RTP; ++rt)
#pragma unroll
        for (int t = 0; t < 2; ++t) acc1[rt][t] = (f32x4){0.f, 0.f, 0.f, 0.f};

      bf16x8 wr1[3][2];   // 3-slot rotation, depth-2 (read ks%3, load (ks+2)%3)
#pragma unroll
      for (int pf = 0; pf < 2; ++pf)
#pragma unroll
        for (int t = 0; t < 2; ++t)
          wr1[pf][t] = *(const bf16x8*)(w1p + (size_t)t * 8192 + (size_t)pf * 512);

#pragma unroll
      for (int ks = 0; ks < NKS1; ++ks) {
        if (ks + 2 < NKS1) {
#pragma unroll
          for (int t = 0; t < 2; ++t)
            wr1[(ks + 2) % 3][t] =
                *(const bf16x8*)(w1p + (size_t)t * 8192 + (size_t)(ks + 2) * 512);
        }
        bf16x8 af[RTP];
#pragma unroll
        for (int rt = 0; rt < RTP; ++rt) {
          const int row = (p * RTP + rt) * 16 + lc;
          const int e   = ks * 32 + lg * 8;
          af[rt] = *(const bf16x8*)&As[row * 512 + (e ^ (lc << 3))];
        }
#pragma unroll
        for (int t = 0; t < 2; ++t)
#pragma unroll
          for (int rt = 0; rt < RTP; ++rt)
            acc1[rt][t] = __builtin_amdgcn_mfma_f32_16x16x32_bf16(
                af[rt], wr1[ks % 3][t], acc1[rt][t], 0, 0, 0);
      }

      // last pass: prefill wr2 so its L2 latency hides under GELU + barrier
      if (p == NP - 1) {
#pragma unroll
        for (int pf = 0; pf < 2; ++pf)
#pragma unroll
          for (int t = 0; t < 2; ++t)
            wr2[pf][t] = *(const bf16x8*)(w2p + (size_t)t * 16384 + (size_t)pf * 512);
      }

      // ---- bias + GELU for this pass's rows -> bf16 h chunk in LDS ----
#pragma unroll
      for (int t = 0; t < 2; ++t) {
        const int pos    = w * 2 + t;
        const float bias = b1[c * CHUNK + pos * 16 + lc];
#pragma unroll
        for (int rt = 0; rt < RTP; ++rt) {
#pragma unroll
          for (int r = 0; r < 4; ++r) {
            const float x  = acc1[rt][t][r] + bias;
            const float hx = gelu_tanh(x);
            const int row  = (p * RTP + rt) * 16 + lg * 4 + r;
            const int e    = pos * 16 + lc;
            Hs[row * 256 + (e ^ ((row & 15) << 3))] = (bf16)hx;
          }
        }
      }
    }
    __syncthreads();   // h chunk visible; wr2 loads were in flight during wait

    // ===== GEMM2: y += h_chunk @ W2[c*256:+256, :] (3-slot, depth-2) =====
#pragma unroll
    for (int s2 = 0; s2 < NKS2C; ++s2) {
      if (s2 + 2 < NKS2C) {
#pragma unroll
        for (int t = 0; t < 2; ++t)
          wr2[(s2 + 2) % 3][t] =
              *(const bf16x8*)(w2p + (size_t)t * 16384 + (size_t)(s2 + 2) * 512);
      }
      bf16x8 hf[RT];
#pragma unroll
      for (int g = 0; g < RT; ++g) {
        const int e = s2 * 32 + lg * 8;
        hf[g] = *(const bf16x8*)&Hs[(g * 16 + lc) * 256 + (e ^ (lc << 3))];
      }
#pragma unroll
      for (int t = 0; t < 2; ++t)
#pragma unroll
        for (int g = 0; g < RT; ++g)
          acc2[g][t] = __builtin_amdgcn_mfma_f32_16x16x32_bf16(
              hf[g], wr2[s2 % 3][t], acc2[g][t], 0, 0, 0);
    }
  }

  // ---- epilogue: +b2, row L2-norm, pad mask, store (no yv array) ----
  float bias2[2];
  bias2[0] = b2[(w * 2 + 0) * 16 + lc];
  bias2[1] = b2[(w * 2 + 1) * 16 + lc];

  float ssq[RT][4];
#pragma unroll
  for (int g = 0; g < RT; ++g)
#pragma unroll
    for (int r = 0; r < 4; ++r) ssq[g][r] = 0.f;

#pragma unroll
  for (int t = 0; t < 2; ++t)
#pragma unroll
    for (int g = 0; g < RT; ++g)
#pragma unroll
      for (int r = 0; r < 4; ++r) {
        const float v = acc2[g][t][r] + bias2[t];
        ssq[g][r] += v * v;
      }

#pragma unroll
  for (int g = 0; g < RT; ++g)
#pragma unroll
    for (int r = 0; r < 4; ++r) {
      float s = ssq[g][r];
      s += __shfl_xor(s, 1);
      s += __shfl_xor(s, 2);
      s += __shfl_xor(s, 4);
      s += __shfl_xor(s, 8);
      ssq[g][r] = s;   // per-wave partial (32 of 256 cols)
    }
  if (lc == 0) {
#pragma unroll
    for (int g = 0; g < RT; ++g)
#pragma unroll
      for (int r = 0; r < 4; ++r)
        Ns[(g * 16 + lg * 4 + r) * 8 + w] = ssq[g][r];
  }
  __syncthreads();

#pragma unroll
  for (int g = 0; g < RT; ++g)
#pragma unroll
    for (int r = 0; r < 4; ++r) {
      const int row = g * 16 + lg * 4 + r;
      if (RV == MT || row < RV) {
        float ss = 0.f;
#pragma unroll
        for (int ww = 0; ww < 8; ++ww) ss += Ns[row * 8 + ww];
        const float scale = (Rid[row] < 0) ? 0.f : (1.f / fmaxf(sqrtf(ss), 1e-12f));
#pragma unroll
        for (int t = 0; t < 2; ++t)
          out[(size_t)(row0 + row) * D_OUT + (w * 2 + t) * 16 + lc] =
              (acc2[g][t][r] + bias2[t]) * scale;
      }
    }
}

// ----------------------------- fused main kernel --------------------------------
__global__ __launch_bounds__(THREADS, 1)
void tagproj_fused(const float* __restrict__ tab, const int* __restrict__ ids,
                   const bf16* __restrict__ w1f, const bf16* __restrict__ w2f,
                   const float* __restrict__ b1, const float* __restrict__ b2,
                   float* __restrict__ out) {
  extern __shared__ __align__(16) char lds[];
  bf16*  As  = (bf16*)(lds + OFF_A);
  bf16*  Hb  = (bf16*)(lds + OFF_H);
  float* Ns  = (float*)(lds + OFF_NS);
  int*   Rid = (int*)(lds + OFF_RID);

  const int tid = threadIdx.x;
  const int w   = tid >> 6;   // wave 0..7
  const int l   = tid & 63;
  const int lg  = l >> 4;     // k-group 0..3
  const int lc  = l & 15;     // row/col within 16-tile
  const int base = blockIdx.x * RPB;

  // 3 full 64-row tiles + one 16-row tail tile (8 valid) = 200 rows, balanced
  for (int tt = 0; tt < 3; ++tt)
    process_tile<4, MT>(tab, ids, w1f, w2f, b1, b2, out,
                        As, Hb, Ns, Rid, base + tt * MT, tid, w, l, lg, lc);
  process_tile<1, 8>(tab, ids, w1f, w2f, b1, b2, out,
                     As, Hb, Ns, Rid, base + 192, tid, w, l, lg, lc);
}

// --------------------------------- launcher ---------------------------------
extern "C" void kernel_launch(void* const* d_in, const int* in_sizes, int n_in,
                              void* d_out, int out_size, void* d_ws, size_t ws_size,
                              hipStream_t stream) {
  const float* tab = (const float*)d_in[0];
  const float* w1  = (const float*)d_in[1];
  const float* b1  = (const float*)d_in[2];
  const float* w2  = (const float*)d_in[3];
  const float* b2  = (const float*)d_in[4];
  const int*   ids = (const int*)d_in[5];
  float* out = (float*)d_out;

  bf16* w1f = (bf16*)d_ws;
  bf16* w2f = w1f + W1F_ELEMS;

  hipLaunchKernelGGL(prep_weights, dim3(384), dim3(256), 0, stream, w1, w2, w1f, w2f);

  (void)hipFuncSetAttribute(reinterpret_cast<const void*>(tagproj_fused),
                            hipFuncAttributeMaxDynamicSharedMemorySize, LDS_TOTAL);
  hipLaunchKernelGGL(tagproj_fused, dim3(NBLK), dim3(THREADS), LDS_TOTAL, stream,
                     tab, ids, w1f, w2f, b1, b2, out);
}